// Round 1
// baseline (1373.581 us; speedup 1.0000x reference)
//
#include <hip/hip_runtime.h>
#include <hip/hip_bf16.h>

// ---------------------------------------------------------------------------
// CTCBridgeSparseSlot on MI355X.
// Pipeline:
//   1. prep_w2t   : W2^T = (W_mem @ W_qkv[:,512:1536])^T  -> bf16 [1024][512]
//      bias2      : b2 = b_mem @ Wsub + b_qkv[512:1536]
//   2. cvt_bf16   : proj_feats f32 -> bf16
//   3. kv_gemm    : kv[65536][1024] = proj_bf16 @ W2 + b2  (bf16 MFMA, bf16 out)
//   4. topk_kernel: per (k,b): window-mean scores, exact top-32 (tie=lower idx),
//                   gaussian window weights, gk gate
//   5. z_gather   : Z[768][512] weighted h_ctc window means (f32)
//   6. seed_chain : q = (tanh((Z@Wkv_k + b) @ W_q + b_q)) @ Wqh + bqh (f32)
//   7. attn_kernel: flash attention, blocks = (k,b,h,chunk), partial m/l/u
//   8. out_chain  : combine partials -> ctx -> @W_attn_out -> @W_o -> *gk -> out
// ---------------------------------------------------------------------------

#define T_LEN 8192
#define DMODEL 512
#define NROWS 768 // 3*8*32

typedef __hip_bfloat16 bf16;
typedef short s16x8 __attribute__((ext_vector_type(8)));
typedef float f32x4 __attribute__((ext_vector_type(4)));
typedef float f4 __attribute__((ext_vector_type(4)));
typedef float f2 __attribute__((ext_vector_type(2)));
typedef struct __attribute__((aligned(16))) { bf16 v[8]; } bf8;

// ---------------- 1. combined weight prep ---------------------------------
// W2[i][j] = sum_l W_mem[i][l] * W_qkv[l][512+j]   (j in [0,1024))
// stored transposed bf16: w2t[j][i]
__global__ __launch_bounds__(256) void prep_w2t(const float* __restrict__ Wmem,
                                                const float* __restrict__ Wqkv,
                                                bf16* __restrict__ w2t) {
  __shared__ __align__(16) float As[16][68]; // As[l][j] = Wqkv[l0+l][512+j0+j]
  __shared__ __align__(16) float Bs[16][68]; // Bs[l][i] = Wmem[i0+i][l0+l]
  int tid = threadIdx.x;
  int j0 = blockIdx.x * 64, i0 = blockIdx.y * 64;
  int ty = tid >> 4, tx = tid & 15;
  float c[4][4];
#pragma unroll
  for (int a = 0; a < 4; a++)
#pragma unroll
    for (int b = 0; b < 4; b++) c[a][b] = 0.f;

  for (int l0 = 0; l0 < 512; l0 += 16) {
    __syncthreads();
    {
      int l = tid >> 4, j4 = (tid & 15) * 4;
      f4 v = *(const f4*)&Wqkv[(size_t)(l0 + l) * 1536 + 512 + j0 + j4];
      *(f4*)&As[l][j4] = v;
    }
    {
      int i = tid >> 2, l4 = (tid & 3) * 4;
      f4 v = *(const f4*)&Wmem[(size_t)(i0 + i) * 512 + l0 + l4];
      Bs[l4 + 0][i] = v[0];
      Bs[l4 + 1][i] = v[1];
      Bs[l4 + 2][i] = v[2];
      Bs[l4 + 3][i] = v[3];
    }
    __syncthreads();
#pragma unroll
    for (int l = 0; l < 16; l++) {
      f4 a = *(f4*)&As[l][ty * 4];
      f4 b = *(f4*)&Bs[l][tx * 4];
#pragma unroll
      for (int jj = 0; jj < 4; jj++)
#pragma unroll
        for (int ii = 0; ii < 4; ii++) c[jj][ii] += a[jj] * b[ii];
    }
  }
#pragma unroll
  for (int jj = 0; jj < 4; jj++)
#pragma unroll
    for (int ii = 0; ii < 4; ii++)
      w2t[(size_t)(j0 + ty * 4 + jj) * 512 + i0 + tx * 4 + ii] =
          __float2bfloat16(c[jj][ii]);
}

__global__ void bias2_kernel(const float* __restrict__ bmem,
                             const float* __restrict__ Wqkv,
                             const float* __restrict__ bqkv,
                             float* __restrict__ b2) {
  int j = blockIdx.x * 256 + threadIdx.x; // [0,1024)
  float acc = bqkv[512 + j];
  for (int l = 0; l < 512; l++) acc += bmem[l] * Wqkv[(size_t)l * 1536 + 512 + j];
  b2[j] = acc;
}

// ---------------- 2. proj -> bf16 -----------------------------------------
__global__ __launch_bounds__(256) void cvt_bf16(const float* __restrict__ x,
                                                bf16* __restrict__ y) {
  int i = blockIdx.x * 256 + threadIdx.x; // 8 elems each, n=33554432
  const f4* p = (const f4*)x;
  f4 a = p[(size_t)i * 2], b = p[(size_t)i * 2 + 1];
  __align__(16) bf16 o[8];
  o[0] = __float2bfloat16(a[0]);
  o[1] = __float2bfloat16(a[1]);
  o[2] = __float2bfloat16(a[2]);
  o[3] = __float2bfloat16(a[3]);
  o[4] = __float2bfloat16(b[0]);
  o[5] = __float2bfloat16(b[1]);
  o[6] = __float2bfloat16(b[2]);
  o[7] = __float2bfloat16(b[3]);
  ((f4*)y)[i] = *(f4*)o;
}

// ---------------- 3. big GEMM: kv = proj_bf16 @ W2 + b2 (bf16 MFMA) -------
// A: [65536][512] bf16 row-major. Bt: [1024][512] bf16 (B transposed).
// C: [65536][1024] bf16. Tile 128x128, BK=32, 4 waves, 4x4 16x16x32 MFMA/wave.
__global__ __launch_bounds__(256) void kv_gemm(const bf16* __restrict__ A,
                                               const bf16* __restrict__ Bt,
                                               const float* __restrict__ bias,
                                               bf16* __restrict__ C) {
  __shared__ __align__(16) bf16 As[128 * 32];
  __shared__ __align__(16) bf16 Bs[128 * 32];
  int tid = threadIdx.x;
  int lane = tid & 63, wave = tid >> 6;
  int wm = wave & 1, wn = wave >> 1;
  int m0 = blockIdx.y * 128, n0 = blockIdx.x * 128;
  int l15 = lane & 15, lq = lane >> 4;
  f32x4 acc[4][4];
#pragma unroll
  for (int mi = 0; mi < 4; mi++)
#pragma unroll
    for (int ni = 0; ni < 4; ni++) acc[mi][ni] = (f32x4){0.f, 0.f, 0.f, 0.f};

  for (int k0 = 0; k0 < 512; k0 += 32) {
    __syncthreads();
#pragma unroll
    for (int t = 0; t < 2; t++) {
      int c = t * 256 + tid;
      int row = c >> 2, kq = c & 3;
      s16x8 av = *(const s16x8*)&A[(size_t)(m0 + row) * 512 + k0 + kq * 8];
      s16x8 bv = *(const s16x8*)&Bt[(size_t)(n0 + row) * 512 + k0 + kq * 8];
      *(s16x8*)&As[c * 8] = av;
      *(s16x8*)&Bs[c * 8] = bv;
    }
    __syncthreads();
    s16x8 af[4], bfr[4];
#pragma unroll
    for (int mi = 0; mi < 4; mi++)
      af[mi] = *(s16x8*)&As[(wm * 64 + mi * 16 + l15) * 32 + lq * 8];
#pragma unroll
    for (int ni = 0; ni < 4; ni++)
      bfr[ni] = *(s16x8*)&Bs[(wn * 64 + ni * 16 + l15) * 32 + lq * 8];
#pragma unroll
    for (int mi = 0; mi < 4; mi++)
#pragma unroll
      for (int ni = 0; ni < 4; ni++)
        acc[mi][ni] = __builtin_amdgcn_mfma_f32_16x16x32_bf16(af[mi], bfr[ni],
                                                              acc[mi][ni], 0, 0, 0);
  }
#pragma unroll
  for (int ni = 0; ni < 4; ni++) {
    int col = n0 + wn * 64 + ni * 16 + l15;
    float bcol = bias[col];
#pragma unroll
    for (int mi = 0; mi < 4; mi++) {
      int row = m0 + wm * 64 + mi * 16 + lq * 4;
      f32x4 v = acc[mi][ni];
#pragma unroll
      for (int r = 0; r < 4; r++)
        C[(size_t)(row + r) * 1024 + col] = __float2bfloat16(v[r] + bcol);
    }
  }
}

// ---------------- 4. top-k spike selection --------------------------------
__global__ __launch_bounds__(128) void topk_kernel(const float* __restrict__ A,
                                                   const int* __restrict__ spikes,
                                                   int* __restrict__ spk_out,
                                                   float* __restrict__ w_out,
                                                   float* __restrict__ winv_out,
                                                   float* __restrict__ gk_out) {
  int kb = blockIdx.x; // (k*8+b) in [0,24)
  int i = threadIdx.x; // [0,128)
  const float* Ab = A + (size_t)kb * T_LEN;
  __shared__ float s_sc[128];
  __shared__ int s_sp[128];
  __shared__ int s_sel[32];
  int t0 = spikes[kb * 128 + i];
  s_sp[i] = t0;
  float sum = 0.f;
  int cnt = 0;
#pragma unroll
  for (int o = -8; o <= 8; o++) {
    int t = t0 + o;
    if (t >= 0 && t < T_LEN) { sum += Ab[t]; cnt++; }
  }
  float sc = (t0 >= 0 && t0 < T_LEN) ? (sum / (float)max(cnt, 1)) : -1e9f;
  s_sc[i] = sc;
  __syncthreads();
  float sci = s_sc[i];
  int rank = 0;
  for (int j = 0; j < 128; j++) {
    float scj = s_sc[j];
    if (scj > sci || (scj == sci && j < i)) rank++;
  }
  if (rank < 32) s_sel[rank] = i;
  __syncthreads();
  if (i < 32) {
    int sel = s_sel[i];
    int spkv = s_sp[sel];
    float conf = s_sc[sel];
    int r = kb * 32 + i;
    spk_out[r] = spkv;
    bool vmask = (spkv >= 0 && spkv < T_LEN);
    float wsum = 0.f;
#pragma unroll
    for (int o = 0; o < 17; o++) {
      int t = spkv + o - 8;
      bool v = vmask && (t >= 0) && (t < T_LEN);
      int tc = min(max(t, 0), T_LEN - 1);
      float off = (float)(o - 8) * 0.25f;
      float g = expf(-0.5f * off * off);
      float wv = v ? g * Ab[tc] : 0.f;
      wsum += wv;
      w_out[r * 17 + o] = wv;
    }
    winv_out[r] = 1.f / (wsum + 1e-6f);
    gk_out[r] = vmask ? (1.f / (1.f + expf(-2.f * conf))) : 0.f;
  }
}

// ---------------- 5. Z gather ---------------------------------------------
__global__ __launch_bounds__(256) void z_gather(const float* __restrict__ hctc,
                                                const int* __restrict__ spk,
                                                const float* __restrict__ warr,
                                                const float* __restrict__ winv,
                                                float* __restrict__ Z) {
  int r = blockIdx.x; // [0,768)
  int tid = threadIdx.x;
  int kb = r >> 5;
  const float* h = hctc + (size_t)kb * T_LEN * DMODEL;
  int sp = spk[r];
  float wi = winv[r];
  float acc0 = 0.f, acc1 = 0.f;
#pragma unroll
  for (int o = 0; o < 17; o++) {
    float wv = warr[r * 17 + o];
    int t = min(max(sp + o - 8, 0), T_LEN - 1);
    const float* hp = h + (size_t)t * DMODEL;
    acc0 += wv * hp[tid];
    acc1 += wv * hp[tid + 256];
  }
  Z[(size_t)r * DMODEL + tid] = acc0 * wi;
  Z[(size_t)r * DMODEL + tid + 256] = acc1 * wi;
}

// ---------------- 6. seed chain: Z -> Kseed -> tanh -> q ------------------
__global__ __launch_bounds__(256) void seed_chain(
    const float* __restrict__ Z, const float* __restrict__ Wkv,
    const float* __restrict__ bkv, const float* __restrict__ Wq,
    const float* __restrict__ bq, const float* __restrict__ Wqkv,
    const float* __restrict__ bqkv, float* __restrict__ qout) {
  __shared__ float Zs[8][512];
  __shared__ float T1[8][512];
  __shared__ float T2[8][512];
  int tid = threadIdx.x;
  int r0 = blockIdx.x * 8;
  int k = r0 >> 8;
  for (int ii = 0; ii < 16; ii++) {
    int idx = tid + ii * 256;
    ((float*)Zs)[idx] = Z[(size_t)r0 * 512 + idx];
  }
  __syncthreads();
  int c0 = tid, c1 = tid + 256;
  { // Kseed = Zs @ Wkv[k][:, :512] + bkv[k][:512]
    const float* W = Wkv + (size_t)k * 512 * 1024;
    float a0[8], a1[8];
#pragma unroll
    for (int i = 0; i < 8; i++) { a0[i] = 0.f; a1[i] = 0.f; }
#pragma unroll 4
    for (int l = 0; l < 512; l++) {
      float w0 = W[(size_t)l * 1024 + c0];
      float w1 = W[(size_t)l * 1024 + c1];
#pragma unroll
      for (int i = 0; i < 8; i++) {
        float z = Zs[i][l];
        a0[i] += z * w0;
        a1[i] += z * w1;
      }
    }
    float bb0 = bkv[k * 1024 + c0], bb1 = bkv[k * 1024 + c1];
#pragma unroll
    for (int i = 0; i < 8; i++) {
      T1[i][c0] = a0[i] + bb0;
      T1[i][c1] = a1[i] + bb1;
    }
  }
  __syncthreads();
  { // T2 = tanh(T1 @ Wq + bq)
    float a0[8], a1[8];
#pragma unroll
    for (int i = 0; i < 8; i++) { a0[i] = 0.f; a1[i] = 0.f; }
#pragma unroll 4
    for (int l = 0; l < 512; l++) {
      float w0 = Wq[(size_t)l * 512 + c0];
      float w1 = Wq[(size_t)l * 512 + c1];
#pragma unroll
      for (int i = 0; i < 8; i++) {
        float z = T1[i][l];
        a0[i] += z * w0;
        a1[i] += z * w1;
      }
    }
    float bb0 = bq[c0], bb1 = bq[c1];
#pragma unroll
    for (int i = 0; i < 8; i++) {
      T2[i][c0] = tanhf(a0[i] + bb0);
      T2[i][c1] = tanhf(a1[i] + bb1);
    }
  }
  __syncthreads();
  { // q = T2 @ Wqkv[:, :512] + bqkv[:512]
    float a0[8], a1[8];
#pragma unroll
    for (int i = 0; i < 8; i++) { a0[i] = 0.f; a1[i] = 0.f; }
#pragma unroll 4
    for (int l = 0; l < 512; l++) {
      float w0 = Wqkv[(size_t)l * 1536 + c0];
      float w1 = Wqkv[(size_t)l * 1536 + c1];
#pragma unroll
      for (int i = 0; i < 8; i++) {
        float z = T2[i][l];
        a0[i] += z * w0;
        a1[i] += z * w1;
      }
    }
    float bb0 = bqkv[c0], bb1 = bqkv[c1];
#pragma unroll
    for (int i = 0; i < 8; i++) {
      qout[(size_t)(r0 + i) * 512 + c0] = a0[i] + bb0;
      qout[(size_t)(r0 + i) * 512 + c1] = a1[i] + bb1;
    }
  }
}

// ---------------- 7. attention (flash, chunked) ---------------------------
// block = (k,b,h,c): 32 queries x 1024 keys. partials m/l/u[64] per (q).
__global__ __launch_bounds__(256) void attn_kernel(const bf16* __restrict__ kv,
                                                   const float* __restrict__ qws,
                                                   float* __restrict__ pm,
                                                   float* __restrict__ pl,
                                                   float* __restrict__ pu) {
  __shared__ __align__(16) float Qs[32][68];
  __shared__ __align__(16) float Kt[64][68]; // Kt[d][t]
  __shared__ __align__(16) float Vs[64][66]; // Vs[t][d]
  __shared__ __align__(16) float Ps[32][68];
  int tid = threadIdx.x;
  int bx = blockIdx.x;
  int c = bx & 7, h = (bx >> 3) & 7, b = (bx >> 6) & 7, k = bx >> 9;
  { // stage Q (scaled by 1/sqrt(64))
    int s2 = tid >> 3, dg = tid & 7;
    int d0 = dg * 8;
    const float* qp = qws + ((size_t)((k * 8 + b) * 32 + s2)) * 512 + h * 64 + d0;
    f4 x = *(const f4*)qp;
    f4 y = *(const f4*)(qp + 4);
    x *= 0.125f;
    y *= 0.125f;
    *(f4*)&Qs[s2][d0] = x;
    *(f4*)&Qs[s2][d0 + 4] = y;
  }
  int q2 = tid >> 4, ts = tid & 15;
  float m0v = -3.0e38f, m1v = -3.0e38f, l0 = 0.f, l1 = 0.f;
  f4 ctx0 = {0.f, 0.f, 0.f, 0.f}, ctx1 = {0.f, 0.f, 0.f, 0.f};
  size_t rowbase = (size_t)b * T_LEN + (size_t)c * 1024;

  for (int tt = 0; tt < 16; tt++) {
    __syncthreads();
    { // stage K(transposed) and V, bf16 -> f32
      int tl = tid >> 2, dg = tid & 3;
      int d0 = dg * 16;
      const bf16* kr = kv + (rowbase + tt * 64 + tl) * 1024 + h * 64 + d0;
      bf8 ka = *(const bf8*)kr;
      bf8 kb_ = *(const bf8*)(kr + 8);
      const bf16* vr = kr + 512;
      bf8 va = *(const bf8*)vr;
      bf8 vb = *(const bf8*)(vr + 8);
#pragma unroll
      for (int j = 0; j < 8; j++) {
        Kt[d0 + j][tl] = __bfloat162float(ka.v[j]);
        Kt[d0 + 8 + j][tl] = __bfloat162float(kb_.v[j]);
        Vs[tl][d0 + j] = __bfloat162float(va.v[j]);
        Vs[tl][d0 + 8 + j] = __bfloat162float(vb.v[j]);
      }
    }
    __syncthreads();
    // ---- S = Q K^T for 2 q-rows x 4 t-cols per thread
    f4 sv0 = {0.f, 0.f, 0.f, 0.f}, sv1 = {0.f, 0.f, 0.f, 0.f};
#pragma unroll
    for (int d4 = 0; d4 < 16; d4++) {
      f4 qa = *(f4*)&Qs[q2 * 2][d4 * 4];
      f4 qb = *(f4*)&Qs[q2 * 2 + 1][d4 * 4];
      f4 k0 = *(f4*)&Kt[d4 * 4 + 0][ts * 4];
      f4 k1 = *(f4*)&Kt[d4 * 4 + 1][ts * 4];
      f4 k2 = *(f4*)&Kt[d4 * 4 + 2][ts * 4];
      f4 k3 = *(f4*)&Kt[d4 * 4 + 3][ts * 4];
#pragma unroll
      for (int j = 0; j < 4; j++) {
        sv0[j] += qa[0] * k0[j] + qa[1] * k1[j] + qa[2] * k2[j] + qa[3] * k3[j];
        sv1[j] += qb[0] * k0[j] + qb[1] * k1[j] + qb[2] * k2[j] + qb[3] * k3[j];
      }
    }
    // ---- online softmax update (per q-row, reduce across 16 t-lanes)
    {
      float tmax = fmaxf(fmaxf(sv0[0], sv0[1]), fmaxf(sv0[2], sv0[3]));
      tmax = fmaxf(tmax, __shfl_xor(tmax, 1, 64));
      tmax = fmaxf(tmax, __shfl_xor(tmax, 2, 64));
      tmax = fmaxf(tmax, __shfl_xor(tmax, 4, 64));
      tmax = fmaxf(tmax, __shfl_xor(tmax, 8, 64));
      float mn = fmaxf(m0v, tmax);
      f4 p;
      float ps = 0.f;
#pragma unroll
      for (int j = 0; j < 4; j++) { p[j] = __expf(sv0[j] - mn); ps += p[j]; }
      ps += __shfl_xor(ps, 1, 64);
      ps += __shfl_xor(ps, 2, 64);
      ps += __shfl_xor(ps, 4, 64);
      ps += __shfl_xor(ps, 8, 64);
      float sc = __expf(m0v - mn);
      l0 = l0 * sc + ps;
      m0v = mn;
      ctx0 *= sc;
      *(f4*)&Ps[q2 * 2][ts * 4] = p;
    }
    {
      float tmax = fmaxf(fmaxf(sv1[0], sv1[1]), fmaxf(sv1[2], sv1[3]));
      tmax = fmaxf(tmax, __shfl_xor(tmax, 1, 64));
      tmax = fmaxf(tmax, __shfl_xor(tmax, 2, 64));
      tmax = fmaxf(tmax, __shfl_xor(tmax, 4, 64));
      tmax = fmaxf(tmax, __shfl_xor(tmax, 8, 64));
      float mn = fmaxf(m1v, tmax);
      f4 p;
      float ps = 0.f;
#pragma unroll
      for (int j = 0; j < 4; j++) { p[j] = __expf(sv1[j] - mn); ps += p[j]; }
      ps += __shfl_xor(ps, 1, 64);
      ps += __shfl_xor(ps, 2, 64);
      ps += __shfl_xor(ps, 4, 64);
      ps += __shfl_xor(ps, 8, 64);
      float sc = __expf(m1v - mn);
      l1 = l1 * sc + ps;
      m1v = mn;
      ctx1 *= sc;
      *(f4*)&Ps[q2 * 2 + 1][ts * 4] = p;
    }
    // ---- ctx += P @ V   (P written/read within same wave: no barrier needed)
#pragma unroll 8
    for (int t = 0; t < 64; t++) {
      float pa = Ps[q2 * 2][t];
      float pb = Ps[q2 * 2 + 1][t];
      f2 va = *(f2*)&Vs[t][ts * 4];
      f2 vb = *(f2*)&Vs[t][ts * 4 + 2];
      ctx0[0] += pa * va[0];
      ctx0[1] += pa * va[1];
      ctx0[2] += pa * vb[0];
      ctx0[3] += pa * vb[1];
      ctx1[0] += pb * va[0];
      ctx1[1] += pb * va[1];
      ctx1[2] += pb * vb[0];
      ctx1[3] += pb * vb[1];
    }
  }
  int pbase = (((k * 8 + b) * 8 + h) * 8 + c) * 32;
  *(f4*)&pu[(size_t)(pbase + q2 * 2) * 64 + ts * 4] = ctx0;
  *(f4*)&pu[(size_t)(pbase + q2 * 2 + 1) * 64 + ts * 4] = ctx1;
  if (ts == 0) {
    pm[pbase + q2 * 2] = m0v;
    pl[pbase + q2 * 2] = l0;
    pm[pbase + q2 * 2 + 1] = m1v;
    pl[pbase + q2 * 2 + 1] = l1;
  }
}

// ---------------- 8. combine + output chain -------------------------------
__global__ __launch_bounds__(256) void out_chain(
    const float* __restrict__ pm, const float* __restrict__ pl,
    const float* __restrict__ pu, const float* __restrict__ Watt,
    const float* __restrict__ batt, const float* __restrict__ Wo,
    const float* __restrict__ bo, const float* __restrict__ gk,
    float* __restrict__ out) {
  __shared__ float Cs[8][512];
  __shared__ float T1[8][512];
  int tid = threadIdx.x;
  int r0 = blockIdx.x * 8;
  { // combine chunk partials -> ctx
    int ri = tid >> 5, hh = (tid >> 2) & 7, dq = tid & 3;
    int d0 = dq * 16;
    int r = r0 + ri;
    int k = r >> 8, b = (r >> 5) & 7, s = r & 31;
    int pb0 = ((((k * 8 + b) * 8 + hh) * 8) * 32) + s; // c=0
    float mstar = -3.0e38f;
#pragma unroll
    for (int cc = 0; cc < 8; cc++) mstar = fmaxf(mstar, pm[pb0 + cc * 32]);
    float ls = 0.f;
    f4 us[4];
#pragma unroll
    for (int t4 = 0; t4 < 4; t4++) us[t4] = (f4){0.f, 0.f, 0.f, 0.f};
#pragma unroll
    for (int cc = 0; cc < 8; cc++) {
      int pidx = pb0 + cc * 32;
      float wv = __expf(pm[pidx] - mstar);
      ls += wv * pl[pidx];
      const f4* up = (const f4*)&pu[(size_t)pidx * 64 + d0];
#pragma unroll
      for (int t4 = 0; t4 < 4; t4++) us[t4] += up[t4] * wv;
    }
    float inv = 1.f / ls;
#pragma unroll
    for (int t4 = 0; t4 < 4; t4++)
#pragma unroll
      for (int j = 0; j < 4; j++) Cs[ri][hh * 64 + d0 + t4 * 4 + j] = us[t4][j] * inv;
  }
  __syncthreads();
  int c0 = tid, c1 = tid + 256;
  { // T1 = Cs @ W_attn_out + b_attn_out
    float a0[8], a1[8];
#pragma unroll
    for (int i = 0; i < 8; i++) { a0[i] = 0.f; a1[i] = 0.f; }
#pragma unroll 4
    for (int l = 0; l < 512; l++) {
      float w0 = Watt[(size_t)l * 512 + c0];
      float w1 = Watt[(size_t)l * 512 + c1];
#pragma unroll
      for (int i = 0; i < 8; i++) {
        float z = Cs[i][l];
        a0[i] += z * w0;
        a1[i] += z * w1;
      }
    }
    float bb0 = batt[c0], bb1 = batt[c1];
#pragma unroll
    for (int i = 0; i < 8; i++) {
      T1[i][c0] = a0[i] + bb0;
      T1[i][c1] = a1[i] + bb1;
    }
  }
  __syncthreads();
  { // out = (T1 @ W_o + b_o) * gk, permuted to (b, k*32+s, d)
    float a0[8], a1[8];
#pragma unroll
    for (int i = 0; i < 8; i++) { a0[i] = 0.f; a1[i] = 0.f; }
#pragma unroll 4
    for (int l = 0; l < 512; l++) {
      float w0 = Wo[(size_t)l * 512 + c0];
      float w1 = Wo[(size_t)l * 512 + c1];
#pragma unroll
      for (int i = 0; i < 8; i++) {
        float z = T1[i][l];
        a0[i] += z * w0;
        a1[i] += z * w1;
      }
    }
    float bb0 = bo[c0], bb1 = bo[c1];
#pragma unroll
    for (int i = 0; i < 8; i++) {
      int r = r0 + i;
      int k = r >> 8, b = (r >> 5) & 7, s = r & 31;
      float g = gk[r];
      size_t orow = (size_t)(b * 96 + k * 32 + s) * 512;
      out[orow + c0] = (a0[i] + bb0) * g;
      out[orow + c1] = (a1[i] + bb1) * g;
    }
  }
}

// ---------------------------------------------------------------------------
extern "C" void kernel_launch(void* const* d_in, const int* in_sizes, int n_in,
                              void* d_out, int out_size, void* d_ws, size_t ws_size,
                              hipStream_t stream) {
  const float* proj = (const float*)d_in[0];
  const float* hctc = (const float*)d_in[1];
  const float* A = (const float*)d_in[2];
  const int* spikes = (const int*)d_in[3];
  const float* Wmem = (const float*)d_in[4];
  const float* bmem = (const float*)d_in[5];
  const float* Wkv = (const float*)d_in[6];
  const float* bkv = (const float*)d_in[7];
  const float* Wq = (const float*)d_in[8];
  const float* bq = (const float*)d_in[9];
  const float* Wqkv = (const float*)d_in[10];
  const float* bqkv = (const float*)d_in[11];
  const float* Watt = (const float*)d_in[12];
  const float* batt = (const float*)d_in[13];
  const float* Wo = (const float*)d_in[14];
  const float* bo = (const float*)d_in[15];
  float* out = (float*)d_out;
  (void)in_sizes; (void)n_in; (void)out_size; (void)ws_size;

  char* w = (char*)d_ws;
  bf16* projb = (bf16*)(w + 0);            //  67108864 B
  bf16* kvb   = (bf16*)(w + 67108864);     // 134217728 B
  bf16* w2t   = (bf16*)(w + 201326592);    //   1048576 B
  float* b2   = (float*)(w + 202375168);   //      4096 B
  int* spk    = (int*)(w + 202379264);     //      3072 B
  float* warr = (float*)(w + 202382336);   //     52224 B
  float* winv = (float*)(w + 202434560);   //      3072 B
  float* gk   = (float*)(w + 202437632);   //      3072 B
  float* Zb   = (float*)(w + 202440704);   //   1572864 B
  float* qws  = (float*)(w + 204013568);   //   1572864 B
  float* pm   = (float*)(w + 205586432);   //    196608 B
  float* pl   = (float*)(w + 205783040);   //    196608 B
  float* pu   = (float*)(w + 205979648);   //  12582912 B -> end 218562560

  prep_w2t<<<dim3(16, 8), 256, 0, stream>>>(Wmem, Wqkv, w2t);
  bias2_kernel<<<4, 256, 0, stream>>>(bmem, Wqkv, bqkv, b2);
  cvt_bf16<<<16384, 256, 0, stream>>>(proj, projb);
  kv_gemm<<<dim3(8, 512), 256, 0, stream>>>(projb, w2t, b2, kvb);
  topk_kernel<<<24, 128, 0, stream>>>(A, spikes, spk, warr, winv, gk);
  z_gather<<<768, 256, 0, stream>>>(hctc, spk, warr, winv, Zb);
  seed_chain<<<96, 256, 0, stream>>>(Zb, Wkv, bkv, Wq, bq, Wqkv, bqkv, qws);
  attn_kernel<<<1536, 256, 0, stream>>>(kvb, qws, pm, pl, pu);
  out_chain<<<96, 256, 0, stream>>>(pm, pl, pu, Watt, batt, Wo, bo, gk, out);
}